// Round 4
// baseline (1578.187 us; speedup 1.0000x reference)
//
#include <hip/hip_runtime.h>

// HeteroGAT: 2-layer bipartite GAT (heads=4,ch=25 concat + edge feat; then heads=1,ch=100).
// R4: gemm main loop has NO LDS. lane=node; x via per-lane global dwordx4 (vmcnt,
//     L1-resident rows shared by the block's 4 waves); W via s_load SGPR double-buffer
//     (lgkmcnt now covers ONLY s_load — R3 mixed ds_read+s_load on one counter, forcing
//     full drains every iter -> 31% VALUBusy). 1KB LDS -> ~8 waves/SIMD to hide drains.

#define NNODES 50000
#define NEDGES 800000
#define SCAN_T 1024
#define SCAN_NBLK ((NNODES + SCAN_T - 1) / SCAN_T)  // 49

// ---------------- ce[h] = sum_c We[h*25+c]*ae[h*25+c] (edge-attn constant) ----------------
__global__ void ce_kernel(const float* __restrict__ WeA, const float* __restrict__ aeA,
                          const float* __restrict__ WeB, const float* __restrict__ aeB,
                          float* __restrict__ ce /*[8]: 0..3=AB, 4..7=BA*/) {
    const float* We = blockIdx.x ? WeB : WeA;
    const float* ae = blockIdx.x ? aeB : aeA;
    __shared__ float s[4];
    int tid = threadIdx.x;
    if (tid < 4) s[tid] = 0.f;
    __syncthreads();
    if (tid < 100) atomicAdd(&s[tid / 25], We[tid] * ae[tid]);
    __syncthreads();
    if (tid < 4) ce[blockIdx.x * 4 + tid] = s[tid];
}

// ---------------- CSR build ----------------
__global__ void count_kernel(const int* __restrict__ eiA, const int* __restrict__ eiB,
                             int E, int* cntA, int* cntB) {
    int i = blockIdx.x * blockDim.x + threadIdx.x;
    if (i < E) atomicAdd(&cntA[eiA[E + i]], 1);
    else if (i < 2 * E) atomicAdd(&cntB[eiB[E + (i - E)]], 1);
}

// inclusive block-scan of cnt into ro[i+1] (no cross-block offset yet) + block totals
__global__ __launch_bounds__(SCAN_T) void scanA_kernel(
    const int* __restrict__ cntA, const int* __restrict__ cntB,
    int* __restrict__ roA, int* __restrict__ roB, int* __restrict__ partial, int N) {
    const int dir = blockIdx.y;
    const int* cnt = dir ? cntB : cntA;
    int* ro = dir ? roB : roA;
    const int tid = threadIdx.x;
    const int i = blockIdx.x * SCAN_T + tid;
    __shared__ int sm[SCAN_T];
    sm[tid] = (i < N) ? cnt[i] : 0;
    __syncthreads();
    for (int off = 1; off < SCAN_T; off <<= 1) {
        int t = (tid >= off) ? sm[tid - off] : 0;
        __syncthreads();
        sm[tid] += t;
        __syncthreads();
    }
    if (i < N) ro[i + 1] = sm[tid];
    if (tid == SCAN_T - 1) partial[dir * 64 + blockIdx.x] = sm[tid];
}

// exclusive scan of per-block totals (49 per direction) — tiny, one block
__global__ void scanB_kernel(int* __restrict__ partial, int nblk) {
    __shared__ int sm[128];
    const int tid = threadIdx.x;
    sm[tid] = ((tid & 63) < nblk) ? partial[tid] : 0;
    __syncthreads();
    if (tid < 2) {
        int run = 0;
        for (int b = 0; b < nblk; ++b) {
            int t = sm[tid * 64 + b];
            sm[tid * 64 + b] = run;
            run += t;
        }
    }
    __syncthreads();
    partial[tid] = sm[tid];
}

// add block offsets; derive cur[i] = row start
__global__ __launch_bounds__(SCAN_T) void scanC_kernel(
    const int* __restrict__ cntA, const int* __restrict__ cntB,
    int* __restrict__ roA, int* __restrict__ roB,
    int* __restrict__ curA, int* __restrict__ curB,
    const int* __restrict__ partial, int N) {
    const int dir = blockIdx.y;
    const int* cnt = dir ? cntB : cntA;
    int* ro = dir ? roB : roA;
    int* cur = dir ? curB : curA;
    const int poff = partial[dir * 64 + blockIdx.x];
    const int i = blockIdx.x * SCAN_T + threadIdx.x;
    if (i < N) {
        int c = cnt[i];
        int r = ro[i + 1] + poff;
        ro[i + 1] = r;
        cur[i] = r - c;
        if (i == 0) ro[0] = 0;
    }
}

__global__ void fill_kernel(const int* __restrict__ eiA, const int* __restrict__ eiB,
                            const float* __restrict__ wA, const float* __restrict__ wB,
                            int E, int* curA, int* curB,
                            int* __restrict__ ssA, int* __restrict__ ssB,
                            float* __restrict__ swA, float* __restrict__ swB) {
    int i = blockIdx.x * blockDim.x + threadIdx.x;
    if (i < E) {
        int s = eiA[i], d = eiA[E + i];
        int pos = atomicAdd(&curA[d], 1);
        ssA[pos] = s; swA[pos] = wA[i];
    } else if (i < 2 * E) {
        int j = i - E;
        int s = eiB[j], d = eiB[E + j];
        int pos = atomicAdd(&curB[d], 1);
        ssB[pos] = s; swB[pos] = wB[j];
    }
}

// ---------------- GEMM [N,K]x[K,100] + fused att[n,h] = sum_c H[n,h*ch+c]*a[h*ch+c] ----------------
// lane = node (64 nodes/block), wave w handles cols [25w, 25w+25).
// x: per-lane global dwordx4 every 4 k (vmcnt; block's 4 waves share rows via L1).
// W: wave-uniform s_load into SGPR double buffer (lgkmcnt covers only SMEM).
// H: direct per-lane stores (lane ranges are mutually contiguous; L2 write-combines).
struct GemmArgs {
    const float* X;
    const float* W;
    const float* a;
    float* H;
    float* att;
};

template <int K, int HEADS>
__global__ __launch_bounds__(256, 8) void gemm_att_kernel(
    GemmArgs g0, GemmArgs g1, GemmArgs g2, GemmArgs g3, int N) {
    const GemmArgs ga[4] = {g0, g1, g2, g3};
    const GemmArgs g = ga[blockIdx.y];
    __shared__ float attp[4][64];  // used only for HEADS==1 cross-wave reduce
    const int tid = threadIdx.x;
    const int lane = tid & 63;
    const int w = tid >> 6;
    const int node0 = blockIdx.x * 64;
    const int node = node0 + lane;
    const bool valid = (node < N);
    const int nclamp = valid ? node : (N - 1);
    const float* xrow = g.X + (size_t)nclamp * K;

    const int c0 = __builtin_amdgcn_readfirstlane(25 * w);  // uniform -> W via s_load
    const float* Wp = g.W + c0;

    float acc[25];
#pragma unroll
    for (int j = 0; j < 25; ++j) acc[j] = 0.f;

    float wb[2][25];
#pragma unroll
    for (int j = 0; j < 25; ++j) wb[0][j] = Wp[j];  // row k=0

    float4 xv = *(const float4*)(xrow);  // k=0..3

    for (int k = 0; k < K; k += 4) {
        // prefetch next x quad (vmcnt — independent of W's lgkmcnt)
        const int knx = (k + 4 < K) ? (k + 4) : (K - 4);
        const float4 xn = *(const float4*)(xrow + knx);
        const float xs[4] = {xv.x, xv.y, xv.z, xv.w};
#pragma unroll
        for (int kk = 0; kk < 4; ++kk) {
            const int kg = k + kk;
            const int nr = (kg + 1 < K) ? (kg + 1) : 0;  // clamped W prefetch row
#pragma unroll
            for (int j = 0; j < 25; ++j) wb[(kk + 1) & 1][j] = Wp[nr * 100 + j];
#pragma unroll
            for (int j = 0; j < 25; ++j) acc[j] = fmaf(xs[kk], wb[kk & 1][j], acc[j]);
        }
        xv = xn;
    }

    // attention partial for this (node, col-range): uniform 'a' reads -> s_load
    float ap = 0.f;
#pragma unroll
    for (int j = 0; j < 25; ++j) ap = fmaf(acc[j], g.a[c0 + j], ap);

    // H store: lane writes 25 contiguous floats; lanes' ranges union to one
    // contiguous 25.6KB block region -> L2 write-combines to full lines.
    if (valid) {
        float* Hp = g.H + (size_t)node * 100 + c0;
#pragma unroll
        for (int j = 0; j < 25; ++j) Hp[j] = acc[j];
    }

    if (HEADS == 4) {
        // head h == wave w; no barrier needed
        if (valid) g.att[(size_t)node * 4 + w] = ap;
    } else {
        attp[w][lane] = ap;
        __syncthreads();
        if (tid < 64 && node0 + tid < N)
            g.att[node0 + tid] = attp[0][tid] + attp[1][tid] + attp[2][tid] + attp[3][tid];
    }
}

// ---------------- layer-1 gather: wave per dst node, heads=4, ch=25, edge weight, elu ----------------
struct Gather4Args {
    const int* ro;
    const int* ss;
    const float* sw;
    const float* hs;   // [Ns,100]
    const float* as_;  // [Ns,4]
    const float* ad;   // [Nd,4]
    const float* ce;   // [4]
    const float* bias; // [100]
    float* outp;       // [Nd,100]
};

__global__ __launch_bounds__(256) void gather4_kernel(Gather4Args ga0, Gather4Args ga1, int Nd) {
    const Gather4Args ga[2] = {ga0, ga1};
    const Gather4Args g = ga[blockIdx.y];
    int wid = (int)((blockIdx.x * blockDim.x + threadIdx.x) >> 6);
    if (wid >= Nd) return;
    const int n = __builtin_amdgcn_readfirstlane(wid);
    const int lane = threadIdx.x & 63;
    const int beg = g.ro[n], end = g.ro[n + 1];
    const int c0 = lane, c1 = 64 + lane;
    const bool has1 = (c1 < 100);
    const int h0 = c0 / 25;
    const int h1 = (c1 / 25) & 3;  // valid head when has1; masked to stay in-bounds otherwise
    const float ce0 = g.ce[h0], ce1 = g.ce[h1];
    const float ad0 = g.ad[n * 4 + h0], ad1 = g.ad[n * 4 + h1];
    float acc0 = 0.f, acc1 = 0.f, d0 = 0.f, d1 = 0.f;
    int p = beg;
    for (; p + 1 < end; p += 2) {
        const int sa = g.ss[p], sb = g.ss[p + 1];
        const float wa = g.sw[p], wb = g.sw[p + 1];
        const float* ara = g.as_ + (size_t)sa * 4;
        const float* arb = g.as_ + (size_t)sb * 4;
        const float* hra = g.hs + (size_t)sa * 100;
        const float* hrb = g.hs + (size_t)sb * 100;
        float la0 = ara[h0] + ad0 + wa * ce0;
        float la1 = ara[h1] + ad1 + wa * ce1;
        float lb0 = arb[h0] + ad0 + wb * ce0;
        float lb1 = arb[h1] + ad1 + wb * ce1;
        la0 = fmaxf(la0, 0.2f * la0); la1 = fmaxf(la1, 0.2f * la1);
        lb0 = fmaxf(lb0, 0.2f * lb0); lb1 = fmaxf(lb1, 0.2f * lb1);
        const float pa0 = __expf(la0), pa1 = __expf(la1);
        const float pb0 = __expf(lb0), pb1 = __expf(lb1);
        const float va0 = hra[c0], vb0 = hrb[c0];
        const float va1 = has1 ? hra[c1] : 0.f;
        const float vb1 = has1 ? hrb[c1] : 0.f;
        acc0 = fmaf(pa0, va0, acc0); acc0 = fmaf(pb0, vb0, acc0);
        acc1 = fmaf(pa1, va1, acc1); acc1 = fmaf(pb1, vb1, acc1);
        d0 += pa0 + pb0;
        d1 += pa1 + pb1;
    }
    if (p < end) {
        const int s = g.ss[p];
        const float w = g.sw[p];
        const float* asrow = g.as_ + (size_t)s * 4;
        float l0 = asrow[h0] + ad0 + w * ce0;
        float l1 = asrow[h1] + ad1 + w * ce1;
        l0 = fmaxf(l0, 0.2f * l0);
        l1 = fmaxf(l1, 0.2f * l1);
        const float p0 = __expf(l0);
        const float p1 = __expf(l1);
        const float* hrow = g.hs + (size_t)s * 100;
        acc0 = fmaf(p0, hrow[c0], acc0);
        acc1 = fmaf(p1, has1 ? hrow[c1] : 0.f, acc1);
        d0 += p0;
        d1 += p1;
    }
    float r0 = (end > beg) ? acc0 / d0 : 0.f;
    float r1 = (end > beg) ? acc1 / d1 : 0.f;
    r0 += g.bias[c0];
    r0 = (r0 > 0.f) ? r0 : (__expf(r0) - 1.f);  // elu
    g.outp[(size_t)n * 100 + c0] = r0;
    if (has1) {
        r1 += g.bias[c1];
        r1 = (r1 > 0.f) ? r1 : (__expf(r1) - 1.f);
        g.outp[(size_t)n * 100 + c1] = r1;
    }
}

// ---------------- layer-2 gather: wave per dst node, heads=1, ch=100, no edge feat, no elu ----------------
struct Gather1Args {
    const int* ro;
    const int* ss;
    const float* hs;   // [Ns,100]
    const float* as_;  // [Ns]
    const float* ad;   // [Nd]
    const float* bias; // [100]
    float* outp;       // [Nd,100]
};

__global__ __launch_bounds__(256) void gather1_kernel(Gather1Args ga0, Gather1Args ga1, int Nd) {
    const Gather1Args ga[2] = {ga0, ga1};
    const Gather1Args g = ga[blockIdx.y];
    int wid = (int)((blockIdx.x * blockDim.x + threadIdx.x) >> 6);
    if (wid >= Nd) return;
    const int n = __builtin_amdgcn_readfirstlane(wid);
    const int lane = threadIdx.x & 63;
    const int beg = g.ro[n], end = g.ro[n + 1];
    const int c0 = lane, c1 = 64 + lane;
    const bool has1 = (c1 < 100);
    const float adn = g.ad[n];
    float acc0 = 0.f, acc1 = 0.f, d0 = 0.f;
    int p = beg;
    for (; p + 1 < end; p += 2) {
        const int sa = g.ss[p], sb = g.ss[p + 1];
        float la = g.as_[sa] + adn;
        float lb = g.as_[sb] + adn;
        la = fmaxf(la, 0.2f * la);
        lb = fmaxf(lb, 0.2f * lb);
        const float pa = __expf(la), pb = __expf(lb);
        const float* hra = g.hs + (size_t)sa * 100;
        const float* hrb = g.hs + (size_t)sb * 100;
        const float va0 = hra[c0], vb0 = hrb[c0];
        const float va1 = has1 ? hra[c1] : 0.f;
        const float vb1 = has1 ? hrb[c1] : 0.f;
        acc0 = fmaf(pa, va0, acc0); acc0 = fmaf(pb, vb0, acc0);
        acc1 = fmaf(pa, va1, acc1); acc1 = fmaf(pb, vb1, acc1);
        d0 += pa + pb;
    }
    if (p < end) {
        const int s = g.ss[p];
        float l = g.as_[s] + adn;
        l = fmaxf(l, 0.2f * l);
        const float pe = __expf(l);
        const float* hrow = g.hs + (size_t)s * 100;
        acc0 = fmaf(pe, hrow[c0], acc0);
        acc1 = fmaf(pe, has1 ? hrow[c1] : 0.f, acc1);
        d0 += pe;
    }
    float r0 = (end > beg) ? acc0 / d0 : 0.f;
    float r1 = (end > beg) ? acc1 / d0 : 0.f;
    g.outp[(size_t)n * 100 + c0] = r0 + g.bias[c0];
    if (has1) g.outp[(size_t)n * 100 + c1] = r1 + g.bias[c1];
}

extern "C" void kernel_launch(void* const* d_in, const int* in_sizes, int n_in,
                              void* d_out, int out_size, void* d_ws, size_t ws_size,
                              hipStream_t stream) {
    const float* x_A   = (const float*)d_in[0];
    const float* x_B   = (const float*)d_in[1];
    const int*   ei_AB = (const int*)d_in[2];
    const int*   ei_BA = (const int*)d_in[3];
    const float* w_AB  = (const float*)d_in[4];
    const float* w_BA  = (const float*)d_in[5];
    const float* l1AB_Ws = (const float*)d_in[6];
    const float* l1AB_Wd = (const float*)d_in[7];
    const float* l1AB_as = (const float*)d_in[8];
    const float* l1AB_ad = (const float*)d_in[9];
    const float* l1AB_We = (const float*)d_in[10];
    const float* l1AB_ae = (const float*)d_in[11];
    const float* l1AB_b  = (const float*)d_in[12];
    const float* l2AB_Ws = (const float*)d_in[13];
    const float* l2AB_Wd = (const float*)d_in[14];
    const float* l2AB_as = (const float*)d_in[15];
    const float* l2AB_ad = (const float*)d_in[16];
    const float* l2AB_b  = (const float*)d_in[17];
    const float* l1BA_Ws = (const float*)d_in[18];
    const float* l1BA_Wd = (const float*)d_in[19];
    const float* l1BA_as = (const float*)d_in[20];
    const float* l1BA_ad = (const float*)d_in[21];
    const float* l1BA_We = (const float*)d_in[22];
    const float* l1BA_ae = (const float*)d_in[23];
    const float* l1BA_b  = (const float*)d_in[24];
    const float* l2BA_Ws = (const float*)d_in[25];
    const float* l2BA_Wd = (const float*)d_in[26];
    const float* l2BA_as = (const float*)d_in[27];
    const float* l2BA_ad = (const float*)d_in[28];
    const float* l2BA_b  = (const float*)d_in[29];

    const int N = NNODES, E = NEDGES;

    // ---- workspace carve (4-byte elements, 64-element aligned) ----
    size_t o = 0;
    auto alloc = [&](size_t n) { size_t r = o; o += (n + 63) & ~(size_t)63; return r; };
    size_t cntA = alloc(N), cntB = alloc(N);
    size_t roA = alloc(N + 1), roB = alloc(N + 1);
    size_t curA = alloc(N), curB = alloc(N);
    size_t ssA = alloc(E), ssB = alloc(E);
    size_t swA = alloc(E), swB = alloc(E);
    size_t ce8 = alloc(8);
    size_t part = alloc(128);
    size_t h1sA = alloc((size_t)N * 100), h1dB = alloc((size_t)N * 100);
    size_t h1sB = alloc((size_t)N * 100), h1dA = alloc((size_t)N * 100);
    size_t a1sA = alloc((size_t)N * 4), a1dB = alloc((size_t)N * 4);
    size_t a1sB = alloc((size_t)N * 4), a1dA = alloc((size_t)N * 4);
    size_t hA1 = alloc((size_t)N * 100), hB1 = alloc((size_t)N * 100);
    (void)ws_size;

    float* wsf = (float*)d_ws;
    int*   wsi = (int*)d_ws;

    // zero edge-count histograms (cntA..cntB contiguous span)
    hipMemsetAsync(wsi + cntA, 0, sizeof(int) * (cntB + N - cntA), stream);

    ce_kernel<<<2, 128, 0, stream>>>(l1AB_We, l1AB_ae, l1BA_We, l1BA_ae, wsf + ce8);

    const int eb = (2 * E + 255) / 256;
    count_kernel<<<eb, 256, 0, stream>>>(ei_AB, ei_BA, E, wsi + cntA, wsi + cntB);
    scanA_kernel<<<dim3(SCAN_NBLK, 2), SCAN_T, 0, stream>>>(
        wsi + cntA, wsi + cntB, wsi + roA, wsi + roB, wsi + part, N);
    scanB_kernel<<<1, 128, 0, stream>>>(wsi + part, SCAN_NBLK);
    scanC_kernel<<<dim3(SCAN_NBLK, 2), SCAN_T, 0, stream>>>(
        wsi + cntA, wsi + cntB, wsi + roA, wsi + roB, wsi + curA, wsi + curB, wsi + part, N);
    fill_kernel<<<eb, 256, 0, stream>>>(ei_AB, ei_BA, w_AB, w_BA, E, wsi + curA, wsi + curB,
                                        wsi + ssA, wsi + ssB, wsf + swA, wsf + swB);

    const int gb = (N + 63) / 64;  // 782
    // layer-1 node transforms (4 independent gemms, one launch)
    {
        GemmArgs g0 = {x_A, l1AB_Ws, l1AB_as, wsf + h1sA, wsf + a1sA};
        GemmArgs g1 = {x_B, l1AB_Wd, l1AB_ad, wsf + h1dB, wsf + a1dB};
        GemmArgs g2 = {x_B, l1BA_Ws, l1BA_as, wsf + h1sB, wsf + a1sB};
        GemmArgs g3 = {x_A, l1BA_Wd, l1BA_ad, wsf + h1dA, wsf + a1dA};
        gemm_att_kernel<128, 4><<<dim3(gb, 4), 256, 0, stream>>>(g0, g1, g2, g3, N);
    }

    const int wb = (N + 3) / 4;  // wave per node, 4 waves/block
    {
        Gather4Args g0 = {wsi + roA, wsi + ssA, wsf + swA, wsf + h1sA, wsf + a1sA,
                          wsf + a1dB, wsf + ce8, l1AB_b, wsf + hB1};
        Gather4Args g1 = {wsi + roB, wsi + ssB, wsf + swB, wsf + h1sB, wsf + a1sB,
                          wsf + a1dA, wsf + ce8 + 4, l1BA_b, wsf + hA1};
        gather4_kernel<<<dim3(wb, 2), 256, 0, stream>>>(g0, g1, N);
    }

    // layer-2 node transforms (reuse layer-1 buffers)
    {
        GemmArgs g0 = {wsf + hA1, l2AB_Ws, l2AB_as, wsf + h1sA, wsf + a1sA};
        GemmArgs g1 = {wsf + hB1, l2AB_Wd, l2AB_ad, wsf + h1dB, wsf + a1dB};
        GemmArgs g2 = {wsf + hB1, l2BA_Ws, l2BA_as, wsf + h1sB, wsf + a1sB};
        GemmArgs g3 = {wsf + hA1, l2BA_Wd, l2BA_ad, wsf + h1dA, wsf + a1dA};
        gemm_att_kernel<100, 1><<<dim3(gb, 4), 256, 0, stream>>>(g0, g1, g2, g3, N);
    }

    float* out = (float*)d_out;
    // oA = BA direction (dst in A) -> d_out[0..5M); oB = AB direction -> d_out[5M..10M)
    {
        Gather1Args g0 = {wsi + roA, wsi + ssA, wsf + h1sA, wsf + a1sA, wsf + a1dB,
                          l2AB_b, out + (size_t)N * 100};
        Gather1Args g1 = {wsi + roB, wsi + ssB, wsf + h1sB, wsf + a1sB, wsf + a1dA,
                          l2BA_b, out};
        gather1_kernel<<<dim3(wb, 2), 256, 0, stream>>>(g0, g1, N);
    }
}

// Round 5
// 1321.301 us; speedup vs baseline: 1.1944x; 1.1944x over previous
//
#include <hip/hip_runtime.h>

// HeteroGAT: 2-layer bipartite GAT (heads=4,ch=25 concat + edge feat; then heads=1,ch=100).
// R5 gemm: launch_bounds(256,4) — R4's (256,8) strangled VGPRs to 32 and serialized W
//   loads (9.5% VALU). 2 nodes/thread (128 nodes/block) halves W s_load traffic per FMA.
//   Loop stays LDS-free (W=s_load/lgkm, X=dwordx4/vmcnt, independent counters).
//   Epilogue LDS transpose (pad 101) -> coalesced H stores (kills 3x write amp, 240->~84MB).

#define NNODES 50000
#define NEDGES 800000
#define SCAN_T 1024
#define SCAN_NBLK ((NNODES + SCAN_T - 1) / SCAN_T)  // 49

// ---------------- ce[h] = sum_c We[h*25+c]*ae[h*25+c] (edge-attn constant) ----------------
__global__ void ce_kernel(const float* __restrict__ WeA, const float* __restrict__ aeA,
                          const float* __restrict__ WeB, const float* __restrict__ aeB,
                          float* __restrict__ ce /*[8]: 0..3=AB, 4..7=BA*/) {
    const float* We = blockIdx.x ? WeB : WeA;
    const float* ae = blockIdx.x ? aeB : aeA;
    __shared__ float s[4];
    int tid = threadIdx.x;
    if (tid < 4) s[tid] = 0.f;
    __syncthreads();
    if (tid < 100) atomicAdd(&s[tid / 25], We[tid] * ae[tid]);
    __syncthreads();
    if (tid < 4) ce[blockIdx.x * 4 + tid] = s[tid];
}

// ---------------- CSR build ----------------
__global__ void count_kernel(const int* __restrict__ eiA, const int* __restrict__ eiB,
                             int E, int* cntA, int* cntB) {
    int i = blockIdx.x * blockDim.x + threadIdx.x;
    if (i < E) atomicAdd(&cntA[eiA[E + i]], 1);
    else if (i < 2 * E) atomicAdd(&cntB[eiB[E + (i - E)]], 1);
}

// inclusive block-scan of cnt into ro[i+1] (no cross-block offset yet) + block totals
__global__ __launch_bounds__(SCAN_T) void scanA_kernel(
    const int* __restrict__ cntA, const int* __restrict__ cntB,
    int* __restrict__ roA, int* __restrict__ roB, int* __restrict__ partial, int N) {
    const int dir = blockIdx.y;
    const int* cnt = dir ? cntB : cntA;
    int* ro = dir ? roB : roA;
    const int tid = threadIdx.x;
    const int i = blockIdx.x * SCAN_T + tid;
    __shared__ int sm[SCAN_T];
    sm[tid] = (i < N) ? cnt[i] : 0;
    __syncthreads();
    for (int off = 1; off < SCAN_T; off <<= 1) {
        int t = (tid >= off) ? sm[tid - off] : 0;
        __syncthreads();
        sm[tid] += t;
        __syncthreads();
    }
    if (i < N) ro[i + 1] = sm[tid];
    if (tid == SCAN_T - 1) partial[dir * 64 + blockIdx.x] = sm[tid];
}

// exclusive scan of per-block totals (49 per direction) — tiny, one block
__global__ void scanB_kernel(int* __restrict__ partial, int nblk) {
    __shared__ int sm[128];
    const int tid = threadIdx.x;
    sm[tid] = ((tid & 63) < nblk) ? partial[tid] : 0;
    __syncthreads();
    if (tid < 2) {
        int run = 0;
        for (int b = 0; b < nblk; ++b) {
            int t = sm[tid * 64 + b];
            sm[tid * 64 + b] = run;
            run += t;
        }
    }
    __syncthreads();
    partial[tid] = sm[tid];
}

// add block offsets; derive cur[i] = row start
__global__ __launch_bounds__(SCAN_T) void scanC_kernel(
    const int* __restrict__ cntA, const int* __restrict__ cntB,
    int* __restrict__ roA, int* __restrict__ roB,
    int* __restrict__ curA, int* __restrict__ curB,
    const int* __restrict__ partial, int N) {
    const int dir = blockIdx.y;
    const int* cnt = dir ? cntB : cntA;
    int* ro = dir ? roB : roA;
    int* cur = dir ? curB : curA;
    const int poff = partial[dir * 64 + blockIdx.x];
    const int i = blockIdx.x * SCAN_T + threadIdx.x;
    if (i < N) {
        int c = cnt[i];
        int r = ro[i + 1] + poff;
        ro[i + 1] = r;
        cur[i] = r - c;
        if (i == 0) ro[0] = 0;
    }
}

__global__ void fill_kernel(const int* __restrict__ eiA, const int* __restrict__ eiB,
                            const float* __restrict__ wA, const float* __restrict__ wB,
                            int E, int* curA, int* curB,
                            int* __restrict__ ssA, int* __restrict__ ssB,
                            float* __restrict__ swA, float* __restrict__ swB) {
    int i = blockIdx.x * blockDim.x + threadIdx.x;
    if (i < E) {
        int s = eiA[i], d = eiA[E + i];
        int pos = atomicAdd(&curA[d], 1);
        ssA[pos] = s; swA[pos] = wA[i];
    } else if (i < 2 * E) {
        int j = i - E;
        int s = eiB[j], d = eiB[E + j];
        int pos = atomicAdd(&curB[d], 1);
        ssB[pos] = s; swB[pos] = wB[j];
    }
}

// ---------------- GEMM [N,K]x[K,100] + fused att[n,h] = sum_c H[n,h*ch+c]*a[h*ch+c] ----------------
// 128 nodes/block; lane owns nodes (lane, lane+64); wave w owns cols [25w,25w+25).
// Loop: W rows via uniform-address loads (s_load, lgkmcnt only), X via per-lane
// dwordx4 (vmcnt). Epilogue: LDS transpose (pad 101, conflict-free) -> coalesced H.
struct GemmArgs {
    const float* X;
    const float* W;
    const float* a;
    float* H;
    float* att;
};

template <int K, int HEADS>
__global__ __launch_bounds__(256, 4) void gemm_att_kernel(
    GemmArgs g0, GemmArgs g1, GemmArgs g2, GemmArgs g3, int N) {
    const GemmArgs ga[4] = {g0, g1, g2, g3};
    const GemmArgs g = ga[blockIdx.y];
    constexpr int S = 101;
    __shared__ float hs_t[64 * S];   // 25.9 KB, epilogue transpose buffer
    __shared__ float attp[4][128];   // HEADS==1 cross-wave reduce
    const int tid = threadIdx.x;
    const int lane = tid & 63;
    const int w = tid >> 6;
    const int node0 = blockIdx.x * 128;
    const int nA = node0 + lane;
    const int nB = node0 + 64 + lane;
    const bool vA = nA < N, vB = nB < N;
    const float* xr0 = g.X + (size_t)(vA ? nA : (N - 1)) * K;
    const float* xr1 = g.X + (size_t)(vB ? nB : (N - 1)) * K;

    const int c0 = 25 * w;  // wave-uniform
    const float* Wp = g.W + c0;

    float acc0[25], acc1[25];
#pragma unroll
    for (int j = 0; j < 25; ++j) { acc0[j] = 0.f; acc1[j] = 0.f; }

    float4 xq0 = *(const float4*)xr0;
    float4 xq1 = *(const float4*)xr1;

    for (int k0 = 0; k0 < K; k0 += 4) {
        // prefetch next x quads (vmcnt — independent of W's lgkmcnt)
        const int knx = (k0 + 4 < K) ? (k0 + 4) : 0;
        const float4 xn0 = *(const float4*)(xr0 + knx);
        const float4 xn1 = *(const float4*)(xr1 + knx);
        const float xs0[4] = {xq0.x, xq0.y, xq0.z, xq0.w};
        const float xs1[4] = {xq1.x, xq1.y, xq1.z, xq1.w};
#pragma unroll
        for (int kk = 0; kk < 4; ++kk) {
            float wr[25];
#pragma unroll
            for (int j = 0; j < 25; ++j) wr[j] = Wp[(k0 + kk) * 100 + j];  // uniform -> s_load
#pragma unroll
            for (int j = 0; j < 25; ++j) {
                acc0[j] = fmaf(xs0[kk], wr[j], acc0[j]);
                acc1[j] = fmaf(xs1[kk], wr[j], acc1[j]);
            }
        }
        xq0 = xn0;
        xq1 = xn1;
    }

    // attention partials (uniform 'a' -> s_load)
    float ap0 = 0.f, ap1 = 0.f;
#pragma unroll
    for (int j = 0; j < 25; ++j) {
        const float av = g.a[c0 + j];
        ap0 = fmaf(acc0[j], av, ap0);
        ap1 = fmaf(acc1[j], av, ap1);
    }
    if (HEADS == 4) {
        if (vA) g.att[(size_t)nA * 4 + w] = ap0;
        if (vB) g.att[(size_t)nB * 4 + w] = ap1;
    } else {
        attp[w][lane] = ap0;
        attp[w][64 + lane] = ap1;
    }

    // ---- epilogue: two 64-node transpose chunks -> coalesced H stores ----
    const int rem = N - node0;
    // chunk A (nodes node0 .. node0+63)
#pragma unroll
    for (int j = 0; j < 25; ++j) hs_t[lane * S + c0 + j] = acc0[j];
    __syncthreads();
    {
        const int limA = ((rem < 64) ? (rem < 0 ? 0 : rem) : 64) * 100;
        float* Hb = g.H + (size_t)node0 * 100;
        for (int i = tid; i < 6400; i += 256) {
            if (i < limA) {
                int nd = i / 100, c = i - nd * 100;
                Hb[i] = hs_t[nd * S + c];
            }
        }
        if (HEADS == 1) {
            if (tid < 128 && node0 + tid < N)
                g.att[node0 + tid] =
                    attp[0][tid] + attp[1][tid] + attp[2][tid] + attp[3][tid];
        }
    }
    __syncthreads();
    // chunk B (nodes node0+64 .. node0+127)
#pragma unroll
    for (int j = 0; j < 25; ++j) hs_t[lane * S + c0 + j] = acc1[j];
    __syncthreads();
    {
        const int remB = rem - 64;
        const int limB = ((remB < 64) ? (remB < 0 ? 0 : remB) : 64) * 100;
        float* Hb = g.H + (size_t)(node0 + 64) * 100;
        for (int i = tid; i < 6400; i += 256) {
            if (i < limB) {
                int nd = i / 100, c = i - nd * 100;
                Hb[i] = hs_t[nd * S + c];
            }
        }
    }
}

// ---------------- layer-1 gather: wave per dst node, heads=4, ch=25, edge weight, elu ----------------
struct Gather4Args {
    const int* ro;
    const int* ss;
    const float* sw;
    const float* hs;   // [Ns,100]
    const float* as_;  // [Ns,4]
    const float* ad;   // [Nd,4]
    const float* ce;   // [4]
    const float* bias; // [100]
    float* outp;       // [Nd,100]
};

__global__ __launch_bounds__(256) void gather4_kernel(Gather4Args ga0, Gather4Args ga1, int Nd) {
    const Gather4Args ga[2] = {ga0, ga1};
    const Gather4Args g = ga[blockIdx.y];
    int wid = (int)((blockIdx.x * blockDim.x + threadIdx.x) >> 6);
    if (wid >= Nd) return;
    const int n = __builtin_amdgcn_readfirstlane(wid);
    const int lane = threadIdx.x & 63;
    const int beg = g.ro[n], end = g.ro[n + 1];
    const int c0 = lane, c1 = 64 + lane;
    const bool has1 = (c1 < 100);
    const int h0 = c0 / 25;
    const int h1 = (c1 / 25) & 3;  // valid head when has1; masked to stay in-bounds otherwise
    const float ce0 = g.ce[h0], ce1 = g.ce[h1];
    const float ad0 = g.ad[n * 4 + h0], ad1 = g.ad[n * 4 + h1];
    float acc0 = 0.f, acc1 = 0.f, d0 = 0.f, d1 = 0.f;
    int p = beg;
    for (; p + 1 < end; p += 2) {
        const int sa = g.ss[p], sb = g.ss[p + 1];
        const float wa = g.sw[p], wb = g.sw[p + 1];
        const float* ara = g.as_ + (size_t)sa * 4;
        const float* arb = g.as_ + (size_t)sb * 4;
        const float* hra = g.hs + (size_t)sa * 100;
        const float* hrb = g.hs + (size_t)sb * 100;
        float la0 = ara[h0] + ad0 + wa * ce0;
        float la1 = ara[h1] + ad1 + wa * ce1;
        float lb0 = arb[h0] + ad0 + wb * ce0;
        float lb1 = arb[h1] + ad1 + wb * ce1;
        la0 = fmaxf(la0, 0.2f * la0); la1 = fmaxf(la1, 0.2f * la1);
        lb0 = fmaxf(lb0, 0.2f * lb0); lb1 = fmaxf(lb1, 0.2f * lb1);
        const float pa0 = __expf(la0), pa1 = __expf(la1);
        const float pb0 = __expf(lb0), pb1 = __expf(lb1);
        const float va0 = hra[c0], vb0 = hrb[c0];
        const float va1 = has1 ? hra[c1] : 0.f;
        const float vb1 = has1 ? hrb[c1] : 0.f;
        acc0 = fmaf(pa0, va0, acc0); acc0 = fmaf(pb0, vb0, acc0);
        acc1 = fmaf(pa1, va1, acc1); acc1 = fmaf(pb1, vb1, acc1);
        d0 += pa0 + pb0;
        d1 += pa1 + pb1;
    }
    if (p < end) {
        const int s = g.ss[p];
        const float w = g.sw[p];
        const float* asrow = g.as_ + (size_t)s * 4;
        float l0 = asrow[h0] + ad0 + w * ce0;
        float l1 = asrow[h1] + ad1 + w * ce1;
        l0 = fmaxf(l0, 0.2f * l0);
        l1 = fmaxf(l1, 0.2f * l1);
        const float p0 = __expf(l0);
        const float p1 = __expf(l1);
        const float* hrow = g.hs + (size_t)s * 100;
        acc0 = fmaf(p0, hrow[c0], acc0);
        acc1 = fmaf(p1, has1 ? hrow[c1] : 0.f, acc1);
        d0 += p0;
        d1 += p1;
    }
    float r0 = (end > beg) ? acc0 / d0 : 0.f;
    float r1 = (end > beg) ? acc1 / d1 : 0.f;
    r0 += g.bias[c0];
    r0 = (r0 > 0.f) ? r0 : (__expf(r0) - 1.f);  // elu
    g.outp[(size_t)n * 100 + c0] = r0;
    if (has1) {
        r1 += g.bias[c1];
        r1 = (r1 > 0.f) ? r1 : (__expf(r1) - 1.f);
        g.outp[(size_t)n * 100 + c1] = r1;
    }
}

// ---------------- layer-2 gather: wave per dst node, heads=1, ch=100, no edge feat, no elu ----------------
struct Gather1Args {
    const int* ro;
    const int* ss;
    const float* hs;   // [Ns,100]
    const float* as_;  // [Ns]
    const float* ad;   // [Nd]
    const float* bias; // [100]
    float* outp;       // [Nd,100]
};

__global__ __launch_bounds__(256) void gather1_kernel(Gather1Args ga0, Gather1Args ga1, int Nd) {
    const Gather1Args ga[2] = {ga0, ga1};
    const Gather1Args g = ga[blockIdx.y];
    int wid = (int)((blockIdx.x * blockDim.x + threadIdx.x) >> 6);
    if (wid >= Nd) return;
    const int n = __builtin_amdgcn_readfirstlane(wid);
    const int lane = threadIdx.x & 63;
    const int beg = g.ro[n], end = g.ro[n + 1];
    const int c0 = lane, c1 = 64 + lane;
    const bool has1 = (c1 < 100);
    const float adn = g.ad[n];
    float acc0 = 0.f, acc1 = 0.f, d0 = 0.f;
    int p = beg;
    for (; p + 1 < end; p += 2) {
        const int sa = g.ss[p], sb = g.ss[p + 1];
        float la = g.as_[sa] + adn;
        float lb = g.as_[sb] + adn;
        la = fmaxf(la, 0.2f * la);
        lb = fmaxf(lb, 0.2f * lb);
        const float pa = __expf(la), pb = __expf(lb);
        const float* hra = g.hs + (size_t)sa * 100;
        const float* hrb = g.hs + (size_t)sb * 100;
        const float va0 = hra[c0], vb0 = hrb[c0];
        const float va1 = has1 ? hra[c1] : 0.f;
        const float vb1 = has1 ? hrb[c1] : 0.f;
        acc0 = fmaf(pa, va0, acc0); acc0 = fmaf(pb, vb0, acc0);
        acc1 = fmaf(pa, va1, acc1); acc1 = fmaf(pb, vb1, acc1);
        d0 += pa + pb;
    }
    if (p < end) {
        const int s = g.ss[p];
        float l = g.as_[s] + adn;
        l = fmaxf(l, 0.2f * l);
        const float pe = __expf(l);
        const float* hrow = g.hs + (size_t)s * 100;
        acc0 = fmaf(pe, hrow[c0], acc0);
        acc1 = fmaf(pe, has1 ? hrow[c1] : 0.f, acc1);
        d0 += pe;
    }
    float r0 = (end > beg) ? acc0 / d0 : 0.f;
    float r1 = (end > beg) ? acc1 / d0 : 0.f;
    g.outp[(size_t)n * 100 + c0] = r0 + g.bias[c0];
    if (has1) g.outp[(size_t)n * 100 + c1] = r1 + g.bias[c1];
}

extern "C" void kernel_launch(void* const* d_in, const int* in_sizes, int n_in,
                              void* d_out, int out_size, void* d_ws, size_t ws_size,
                              hipStream_t stream) {
    const float* x_A   = (const float*)d_in[0];
    const float* x_B   = (const float*)d_in[1];
    const int*   ei_AB = (const int*)d_in[2];
    const int*   ei_BA = (const int*)d_in[3];
    const float* w_AB  = (const float*)d_in[4];
    const float* w_BA  = (const float*)d_in[5];
    const float* l1AB_Ws = (const float*)d_in[6];
    const float* l1AB_Wd = (const float*)d_in[7];
    const float* l1AB_as = (const float*)d_in[8];
    const float* l1AB_ad = (const float*)d_in[9];
    const float* l1AB_We = (const float*)d_in[10];
    const float* l1AB_ae = (const float*)d_in[11];
    const float* l1AB_b  = (const float*)d_in[12];
    const float* l2AB_Ws = (const float*)d_in[13];
    const float* l2AB_Wd = (const float*)d_in[14];
    const float* l2AB_as = (const float*)d_in[15];
    const float* l2AB_ad = (const float*)d_in[16];
    const float* l2AB_b  = (const float*)d_in[17];
    const float* l1BA_Ws = (const float*)d_in[18];
    const float* l1BA_Wd = (const float*)d_in[19];
    const float* l1BA_as = (const float*)d_in[20];
    const float* l1BA_ad = (const float*)d_in[21];
    const float* l1BA_We = (const float*)d_in[22];
    const float* l1BA_ae = (const float*)d_in[23];
    const float* l1BA_b  = (const float*)d_in[24];
    const float* l2BA_Ws = (const float*)d_in[25];
    const float* l2BA_Wd = (const float*)d_in[26];
    const float* l2BA_as = (const float*)d_in[27];
    const float* l2BA_ad = (const float*)d_in[28];
    const float* l2BA_b  = (const float*)d_in[29];

    const int N = NNODES, E = NEDGES;

    // ---- workspace carve (4-byte elements, 64-element aligned) ----
    size_t o = 0;
    auto alloc = [&](size_t n) { size_t r = o; o += (n + 63) & ~(size_t)63; return r; };
    size_t cntA = alloc(N), cntB = alloc(N);
    size_t roA = alloc(N + 1), roB = alloc(N + 1);
    size_t curA = alloc(N), curB = alloc(N);
    size_t ssA = alloc(E), ssB = alloc(E);
    size_t swA = alloc(E), swB = alloc(E);
    size_t ce8 = alloc(8);
    size_t part = alloc(128);
    size_t h1sA = alloc((size_t)N * 100), h1dB = alloc((size_t)N * 100);
    size_t h1sB = alloc((size_t)N * 100), h1dA = alloc((size_t)N * 100);
    size_t a1sA = alloc((size_t)N * 4), a1dB = alloc((size_t)N * 4);
    size_t a1sB = alloc((size_t)N * 4), a1dA = alloc((size_t)N * 4);
    size_t hA1 = alloc((size_t)N * 100), hB1 = alloc((size_t)N * 100);
    (void)ws_size;

    float* wsf = (float*)d_ws;
    int*   wsi = (int*)d_ws;

    // zero edge-count histograms (cntA..cntB contiguous span)
    hipMemsetAsync(wsi + cntA, 0, sizeof(int) * (cntB + N - cntA), stream);

    ce_kernel<<<2, 128, 0, stream>>>(l1AB_We, l1AB_ae, l1BA_We, l1BA_ae, wsf + ce8);

    const int eb = (2 * E + 255) / 256;
    count_kernel<<<eb, 256, 0, stream>>>(ei_AB, ei_BA, E, wsi + cntA, wsi + cntB);
    scanA_kernel<<<dim3(SCAN_NBLK, 2), SCAN_T, 0, stream>>>(
        wsi + cntA, wsi + cntB, wsi + roA, wsi + roB, wsi + part, N);
    scanB_kernel<<<1, 128, 0, stream>>>(wsi + part, SCAN_NBLK);
    scanC_kernel<<<dim3(SCAN_NBLK, 2), SCAN_T, 0, stream>>>(
        wsi + cntA, wsi + cntB, wsi + roA, wsi + roB, wsi + curA, wsi + curB, wsi + part, N);
    fill_kernel<<<eb, 256, 0, stream>>>(ei_AB, ei_BA, w_AB, w_BA, E, wsi + curA, wsi + curB,
                                        wsi + ssA, wsi + ssB, wsf + swA, wsf + swB);

    const int gb = (N + 127) / 128;  // 391
    // layer-1 node transforms (4 independent gemms, one launch)
    {
        GemmArgs g0 = {x_A, l1AB_Ws, l1AB_as, wsf + h1sA, wsf + a1sA};
        GemmArgs g1 = {x_B, l1AB_Wd, l1AB_ad, wsf + h1dB, wsf + a1dB};
        GemmArgs g2 = {x_B, l1BA_Ws, l1BA_as, wsf + h1sB, wsf + a1sB};
        GemmArgs g3 = {x_A, l1BA_Wd, l1BA_ad, wsf + h1dA, wsf + a1dA};
        gemm_att_kernel<128, 4><<<dim3(gb, 4), 256, 0, stream>>>(g0, g1, g2, g3, N);
    }

    const int wb = (N + 3) / 4;  // wave per node, 4 waves/block
    {
        Gather4Args g0 = {wsi + roA, wsi + ssA, wsf + swA, wsf + h1sA, wsf + a1sA,
                          wsf + a1dB, wsf + ce8, l1AB_b, wsf + hB1};
        Gather4Args g1 = {wsi + roB, wsi + ssB, wsf + swB, wsf + h1sB, wsf + a1sB,
                          wsf + a1dA, wsf + ce8 + 4, l1BA_b, wsf + hA1};
        gather4_kernel<<<dim3(wb, 2), 256, 0, stream>>>(g0, g1, N);
    }

    // layer-2 node transforms (reuse layer-1 buffers)
    {
        GemmArgs g0 = {wsf + hA1, l2AB_Ws, l2AB_as, wsf + h1sA, wsf + a1sA};
        GemmArgs g1 = {wsf + hB1, l2AB_Wd, l2AB_ad, wsf + h1dB, wsf + a1dB};
        GemmArgs g2 = {wsf + hB1, l2BA_Ws, l2BA_as, wsf + h1sB, wsf + a1sB};
        GemmArgs g3 = {wsf + hA1, l2BA_Wd, l2BA_ad, wsf + h1dA, wsf + a1dA};
        gemm_att_kernel<100, 1><<<dim3(gb, 4), 256, 0, stream>>>(g0, g1, g2, g3, N);
    }

    float* out = (float*)d_out;
    // oA = BA direction (dst in A) -> d_out[0..5M); oB = AB direction -> d_out[5M..10M)
    {
        Gather1Args g0 = {wsi + roA, wsi + ssA, wsf + h1sA, wsf + a1sA, wsf + a1dB,
                          l2AB_b, out + (size_t)N * 100};
        Gather1Args g1 = {wsi + roB, wsi + ssB, wsf + h1sB, wsf + a1sB, wsf + a1dA,
                          l2BA_b, out};
        gather1_kernel<<<dim3(wb, 2), 256, 0, stream>>>(g0, g1, N);
    }
}

// Round 6
// 1241.771 us; speedup vs baseline: 1.2709x; 1.0640x over previous
//
#include <hip/hip_runtime.h>

// HeteroGAT: 2-layer bipartite GAT (heads=4,ch=25 concat + edge feat; then heads=1,ch=100).
// R6: layer-1 gather was HBM-bound (320us, 61% peak, ~470B/edge random reads).
//   -> layer-1 src tables packed bf16 [N][104] (100 h + 4 a_src), 208B/row: halves
//      random bytes/edge and folds the a_src lookup into the same row.
//   -> dst-role gemms store NO H (reference uses hd only for a_dst) — 2x20MB writes gone.
//   Layer-2 stays fp32 (absmax headroom check before quantizing output-facing h2).

#define NNODES 50000
#define NEDGES 800000
#define SCAN_T 1024
#define SCAN_NBLK ((NNODES + SCAN_T - 1) / SCAN_T)  // 49

typedef unsigned short u16;
typedef unsigned int u32;

__device__ __forceinline__ float b2f(u16 u) {
    union { u32 i; float f; } x;
    x.i = ((u32)u) << 16;
    return x.f;
}
__device__ __forceinline__ u16 f2b(float f) {  // RN-even
    union { float f; u32 i; } x;
    x.f = f;
    u32 r = x.i + 0x7FFFu + ((x.i >> 16) & 1u);
    return (u16)(r >> 16);
}

// ---------------- ce[h] = sum_c We[h*25+c]*ae[h*25+c] (edge-attn constant) ----------------
__global__ void ce_kernel(const float* __restrict__ WeA, const float* __restrict__ aeA,
                          const float* __restrict__ WeB, const float* __restrict__ aeB,
                          float* __restrict__ ce /*[8]: 0..3=AB, 4..7=BA*/) {
    const float* We = blockIdx.x ? WeB : WeA;
    const float* ae = blockIdx.x ? aeB : aeA;
    __shared__ float s[4];
    int tid = threadIdx.x;
    if (tid < 4) s[tid] = 0.f;
    __syncthreads();
    if (tid < 100) atomicAdd(&s[tid / 25], We[tid] * ae[tid]);
    __syncthreads();
    if (tid < 4) ce[blockIdx.x * 4 + tid] = s[tid];
}

// ---------------- CSR build ----------------
__global__ void count_kernel(const int* __restrict__ eiA, const int* __restrict__ eiB,
                             int E, int* cntA, int* cntB) {
    int i = blockIdx.x * blockDim.x + threadIdx.x;
    if (i < E) atomicAdd(&cntA[eiA[E + i]], 1);
    else if (i < 2 * E) atomicAdd(&cntB[eiB[E + (i - E)]], 1);
}

__global__ __launch_bounds__(SCAN_T) void scanA_kernel(
    const int* __restrict__ cntA, const int* __restrict__ cntB,
    int* __restrict__ roA, int* __restrict__ roB, int* __restrict__ partial, int N) {
    const int dir = blockIdx.y;
    const int* cnt = dir ? cntB : cntA;
    int* ro = dir ? roB : roA;
    const int tid = threadIdx.x;
    const int i = blockIdx.x * SCAN_T + tid;
    __shared__ int sm[SCAN_T];
    sm[tid] = (i < N) ? cnt[i] : 0;
    __syncthreads();
    for (int off = 1; off < SCAN_T; off <<= 1) {
        int t = (tid >= off) ? sm[tid - off] : 0;
        __syncthreads();
        sm[tid] += t;
        __syncthreads();
    }
    if (i < N) ro[i + 1] = sm[tid];
    if (tid == SCAN_T - 1) partial[dir * 64 + blockIdx.x] = sm[tid];
}

__global__ void scanB_kernel(int* __restrict__ partial, int nblk) {
    __shared__ int sm[128];
    const int tid = threadIdx.x;
    sm[tid] = ((tid & 63) < nblk) ? partial[tid] : 0;
    __syncthreads();
    if (tid < 2) {
        int run = 0;
        for (int b = 0; b < nblk; ++b) {
            int t = sm[tid * 64 + b];
            sm[tid * 64 + b] = run;
            run += t;
        }
    }
    __syncthreads();
    partial[tid] = sm[tid];
}

__global__ __launch_bounds__(SCAN_T) void scanC_kernel(
    const int* __restrict__ cntA, const int* __restrict__ cntB,
    int* __restrict__ roA, int* __restrict__ roB,
    int* __restrict__ curA, int* __restrict__ curB,
    const int* __restrict__ partial, int N) {
    const int dir = blockIdx.y;
    const int* cnt = dir ? cntB : cntA;
    int* ro = dir ? roB : roA;
    int* cur = dir ? curB : curA;
    const int poff = partial[dir * 64 + blockIdx.x];
    const int i = blockIdx.x * SCAN_T + threadIdx.x;
    if (i < N) {
        int c = cnt[i];
        int r = ro[i + 1] + poff;
        ro[i + 1] = r;
        cur[i] = r - c;
        if (i == 0) ro[0] = 0;
    }
}

__global__ void fill_kernel(const int* __restrict__ eiA, const int* __restrict__ eiB,
                            const float* __restrict__ wA, const float* __restrict__ wB,
                            int E, int* curA, int* curB,
                            int* __restrict__ ssA, int* __restrict__ ssB,
                            float* __restrict__ swA, float* __restrict__ swB) {
    int i = blockIdx.x * blockDim.x + threadIdx.x;
    if (i < E) {
        int s = eiA[i], d = eiA[E + i];
        int pos = atomicAdd(&curA[d], 1);
        ssA[pos] = s; swA[pos] = wA[i];
    } else if (i < 2 * E) {
        int j = i - E;
        int s = eiB[j], d = eiB[E + j];
        int pos = atomicAdd(&curB[d], 1);
        ssB[pos] = s; swB[pos] = wB[j];
    }
}

// ---------------- GEMM [N,K]x[K,100] + fused att ----------------
// 128 nodes/block; lane owns nodes (lane, lane+64); wave w owns cols [25w,25w+25).
// Loop: W via uniform-address loads (s_load/lgkm), X via per-lane dwordx4 (vmcnt).
// HEADS==4 src role (H!=null): epilogue packs bf16 [node][104] (100 h + 4 a_src).
// HEADS==4 dst role (H==null): att[N,4] fp32 only.
// HEADS==1 src role: fp32 H (LDS transpose) + att[N]; dst role: att[N] only.
struct GemmArgs {
    const float* X;
    const float* W;
    const float* a;
    void* H;
    float* att;
};

template <int K, int HEADS>
__global__ __launch_bounds__(256, 4) void gemm_att_kernel(
    GemmArgs g0, GemmArgs g1, GemmArgs g2, GemmArgs g3, int N) {
    const GemmArgs ga[4] = {g0, g1, g2, g3};
    const GemmArgs g = ga[blockIdx.y];
    constexpr int SMEM_BYTES = (HEADS == 4) ? (64 * 106 * 2) : (64 * 101 * 4 + 4 * 128 * 4);
    __shared__ __align__(16) char smem[SMEM_BYTES];
    const int tid = threadIdx.x;
    const int lane = tid & 63;
    const int w = tid >> 6;
    const int node0 = blockIdx.x * 128;
    const int nA = node0 + lane;
    const int nB = node0 + 64 + lane;
    const bool vA = nA < N, vB = nB < N;
    const float* xr0 = g.X + (size_t)(vA ? nA : (N - 1)) * K;
    const float* xr1 = g.X + (size_t)(vB ? nB : (N - 1)) * K;

    const int c0 = 25 * w;  // wave-uniform
    const float* Wp = g.W + c0;

    float acc0[25], acc1[25];
#pragma unroll
    for (int j = 0; j < 25; ++j) { acc0[j] = 0.f; acc1[j] = 0.f; }

    float4 xq0 = *(const float4*)xr0;
    float4 xq1 = *(const float4*)xr1;

    for (int k0 = 0; k0 < K; k0 += 4) {
        const int knx = (k0 + 4 < K) ? (k0 + 4) : 0;
        const float4 xn0 = *(const float4*)(xr0 + knx);
        const float4 xn1 = *(const float4*)(xr1 + knx);
        const float xs0[4] = {xq0.x, xq0.y, xq0.z, xq0.w};
        const float xs1[4] = {xq1.x, xq1.y, xq1.z, xq1.w};
#pragma unroll
        for (int kk = 0; kk < 4; ++kk) {
            float wr[25];
#pragma unroll
            for (int j = 0; j < 25; ++j) wr[j] = Wp[(k0 + kk) * 100 + j];  // uniform -> s_load
#pragma unroll
            for (int j = 0; j < 25; ++j) {
                acc0[j] = fmaf(xs0[kk], wr[j], acc0[j]);
                acc1[j] = fmaf(xs1[kk], wr[j], acc1[j]);
            }
        }
        xq0 = xn0;
        xq1 = xn1;
    }

    float ap0 = 0.f, ap1 = 0.f;
#pragma unroll
    for (int j = 0; j < 25; ++j) {
        const float av = g.a[c0 + j];
        ap0 = fmaf(acc0[j], av, ap0);
        ap1 = fmaf(acc1[j], av, ap1);
    }

    const int rem = N - node0;
    if (HEADS == 4) {
        if (g.H == nullptr) {  // dst role: a_dst only
            if (vA) g.att[(size_t)nA * 4 + w] = ap0;
            if (vB) g.att[(size_t)nB * 4 + w] = ap1;
        } else {               // src role: packed bf16 rows [104], LDS stride 106 (odd uints)
            u16* sh = (u16*)smem;
            u32* sh32 = (u32*)smem;
            // chunk A
#pragma unroll
            for (int j = 0; j < 25; ++j) sh[lane * 106 + c0 + j] = f2b(acc0[j]);
            sh[lane * 106 + 100 + w] = f2b(ap0);
            __syncthreads();
            {
                const int limA = ((rem < 64) ? rem : 64) * 52;
                u32* Hb = (u32*)g.H + (size_t)node0 * 52;
                for (int i = tid; i < 64 * 52; i += 256) {
                    if (i < limA) {
                        int nd = i / 52;
                        Hb[i] = sh32[nd * 53 + (i - nd * 52)];
                    }
                }
            }
            __syncthreads();
            // chunk B
#pragma unroll
            for (int j = 0; j < 25; ++j) sh[lane * 106 + c0 + j] = f2b(acc1[j]);
            sh[lane * 106 + 100 + w] = f2b(ap1);
            __syncthreads();
            {
                const int remB = rem - 64;
                const int limB = ((remB < 64) ? (remB < 0 ? 0 : remB) : 64) * 52;
                u32* Hb = (u32*)g.H + (size_t)(node0 + 64) * 52;
                for (int i = tid; i < 64 * 52; i += 256) {
                    if (i < limB) {
                        int nd = i / 52;
                        Hb[i] = sh32[nd * 53 + (i - nd * 52)];
                    }
                }
            }
        }
    } else {
        constexpr int S = 101;
        float* hs_t = (float*)smem;
        float* attp = (float*)(smem + 64 * S * 4);
        attp[w * 128 + lane] = ap0;
        attp[w * 128 + 64 + lane] = ap1;
        if (g.H != nullptr) {
            float* Hf = (float*)g.H;
            // chunk A
#pragma unroll
            for (int j = 0; j < 25; ++j) hs_t[lane * S + c0 + j] = acc0[j];
            __syncthreads();
            {
                const int limA = ((rem < 64) ? rem : 64) * 100;
                float* Hb = Hf + (size_t)node0 * 100;
                for (int i = tid; i < 6400; i += 256) {
                    if (i < limA) {
                        int nd = i / 100;
                        Hb[i] = hs_t[nd * S + (i - nd * 100)];
                    }
                }
                if (tid < 128 && node0 + tid < N)
                    g.att[node0 + tid] =
                        attp[tid] + attp[128 + tid] + attp[256 + tid] + attp[384 + tid];
            }
            __syncthreads();
            // chunk B
#pragma unroll
            for (int j = 0; j < 25; ++j) hs_t[lane * S + c0 + j] = acc1[j];
            __syncthreads();
            {
                const int remB = rem - 64;
                const int limB = ((remB < 64) ? (remB < 0 ? 0 : remB) : 64) * 100;
                float* Hb = Hf + (size_t)(node0 + 64) * 100;
                for (int i = tid; i < 6400; i += 256) {
                    if (i < limB) {
                        int nd = i / 100;
                        Hb[i] = hs_t[nd * S + (i - nd * 100)];
                    }
                }
            }
        } else {
            __syncthreads();
            if (tid < 128 && node0 + tid < N)
                g.att[node0 + tid] =
                    attp[tid] + attp[128 + tid] + attp[256 + tid] + attp[384 + tid];
        }
    }
}

// ---------------- layer-1 gather: wave per dst node, packed bf16 src rows ----------------
struct Gather4Args {
    const int* ro;
    const int* ss;
    const float* sw;
    const u16* hp;     // [Ns][104] bf16: 0..99 h, 100..103 a_src
    const float* ad;   // [Nd,4] fp32
    const float* ce;   // [4]
    const float* bias; // [100]
    float* outp;       // [Nd,100]
};

__global__ __launch_bounds__(256) void gather4_kernel(Gather4Args ga0, Gather4Args ga1, int Nd) {
    const Gather4Args ga[2] = {ga0, ga1};
    const Gather4Args g = ga[blockIdx.y];
    int wid = (int)((blockIdx.x * blockDim.x + threadIdx.x) >> 6);
    if (wid >= Nd) return;
    const int n = __builtin_amdgcn_readfirstlane(wid);
    const int lane = threadIdx.x & 63;
    const int beg = g.ro[n], end = g.ro[n + 1];
    const int c0 = lane, c1 = 64 + lane;
    const bool has1 = (c1 < 100);
    const int h0 = c0 / 25;
    const int h1 = (c1 / 25) & 3;
    const float ce0 = g.ce[h0], ce1 = g.ce[h1];
    const float ad0 = g.ad[n * 4 + h0], ad1 = g.ad[n * 4 + h1];
    float acc0 = 0.f, acc1 = 0.f, d0 = 0.f, d1 = 0.f;
    int p = beg;
    for (; p + 1 < end; p += 2) {
        const int sa = g.ss[p], sb = g.ss[p + 1];
        const float wa = g.sw[p], wb = g.sw[p + 1];
        const u16* ra = g.hp + (size_t)sa * 104;
        const u16* rb = g.hp + (size_t)sb * 104;
        float la0 = b2f(ra[100 + h0]) + ad0 + wa * ce0;
        float la1 = b2f(ra[100 + h1]) + ad1 + wa * ce1;
        float lb0 = b2f(rb[100 + h0]) + ad0 + wb * ce0;
        float lb1 = b2f(rb[100 + h1]) + ad1 + wb * ce1;
        la0 = fmaxf(la0, 0.2f * la0); la1 = fmaxf(la1, 0.2f * la1);
        lb0 = fmaxf(lb0, 0.2f * lb0); lb1 = fmaxf(lb1, 0.2f * lb1);
        const float pa0 = __expf(la0), pa1 = __expf(la1);
        const float pb0 = __expf(lb0), pb1 = __expf(lb1);
        const float va0 = b2f(ra[c0]), vb0 = b2f(rb[c0]);
        const float va1 = has1 ? b2f(ra[c1]) : 0.f;
        const float vb1 = has1 ? b2f(rb[c1]) : 0.f;
        acc0 = fmaf(pa0, va0, acc0); acc0 = fmaf(pb0, vb0, acc0);
        acc1 = fmaf(pa1, va1, acc1); acc1 = fmaf(pb1, vb1, acc1);
        d0 += pa0 + pb0;
        d1 += pa1 + pb1;
    }
    if (p < end) {
        const int s = g.ss[p];
        const float ww = g.sw[p];
        const u16* ra = g.hp + (size_t)s * 104;
        float l0 = b2f(ra[100 + h0]) + ad0 + ww * ce0;
        float l1 = b2f(ra[100 + h1]) + ad1 + ww * ce1;
        l0 = fmaxf(l0, 0.2f * l0);
        l1 = fmaxf(l1, 0.2f * l1);
        const float p0 = __expf(l0);
        const float p1 = __expf(l1);
        acc0 = fmaf(p0, b2f(ra[c0]), acc0);
        acc1 = fmaf(p1, has1 ? b2f(ra[c1]) : 0.f, acc1);
        d0 += p0;
        d1 += p1;
    }
    float r0 = (end > beg) ? acc0 / d0 : 0.f;
    float r1 = (end > beg) ? acc1 / d1 : 0.f;
    r0 += g.bias[c0];
    r0 = (r0 > 0.f) ? r0 : (__expf(r0) - 1.f);  // elu
    g.outp[(size_t)n * 100 + c0] = r0;
    if (has1) {
        r1 += g.bias[c1];
        r1 = (r1 > 0.f) ? r1 : (__expf(r1) - 1.f);
        g.outp[(size_t)n * 100 + c1] = r1;
    }
}

// ---------------- layer-2 gather: wave per dst node, heads=1, ch=100, fp32 ----------------
struct Gather1Args {
    const int* ro;
    const int* ss;
    const float* hs;   // [Ns,100]
    const float* as_;  // [Ns]
    const float* ad;   // [Nd]
    const float* bias; // [100]
    float* outp;       // [Nd,100]
};

__global__ __launch_bounds__(256) void gather1_kernel(Gather1Args ga0, Gather1Args ga1, int Nd) {
    const Gather1Args ga[2] = {ga0, ga1};
    const Gather1Args g = ga[blockIdx.y];
    int wid = (int)((blockIdx.x * blockDim.x + threadIdx.x) >> 6);
    if (wid >= Nd) return;
    const int n = __builtin_amdgcn_readfirstlane(wid);
    const int lane = threadIdx.x & 63;
    const int beg = g.ro[n], end = g.ro[n + 1];
    const int c0 = lane, c1 = 64 + lane;
    const bool has1 = (c1 < 100);
    const float adn = g.ad[n];
    float acc0 = 0.f, acc1 = 0.f, d0 = 0.f;
    int p = beg;
    for (; p + 1 < end; p += 2) {
        const int sa = g.ss[p], sb = g.ss[p + 1];
        float la = g.as_[sa] + adn;
        float lb = g.as_[sb] + adn;
        la = fmaxf(la, 0.2f * la);
        lb = fmaxf(lb, 0.2f * lb);
        const float pa = __expf(la), pb = __expf(lb);
        const float* hra = g.hs + (size_t)sa * 100;
        const float* hrb = g.hs + (size_t)sb * 100;
        const float va0 = hra[c0], vb0 = hrb[c0];
        const float va1 = has1 ? hra[c1] : 0.f;
        const float vb1 = has1 ? hrb[c1] : 0.f;
        acc0 = fmaf(pa, va0, acc0); acc0 = fmaf(pb, vb0, acc0);
        acc1 = fmaf(pa, va1, acc1); acc1 = fmaf(pb, vb1, acc1);
        d0 += pa + pb;
    }
    if (p < end) {
        const int s = g.ss[p];
        float l = g.as_[s] + adn;
        l = fmaxf(l, 0.2f * l);
        const float pe = __expf(l);
        const float* hrow = g.hs + (size_t)s * 100;
        acc0 = fmaf(pe, hrow[c0], acc0);
        acc1 = fmaf(pe, has1 ? hrow[c1] : 0.f, acc1);
        d0 += pe;
    }
    float r0 = (end > beg) ? acc0 / d0 : 0.f;
    float r1 = (end > beg) ? acc1 / d0 : 0.f;
    g.outp[(size_t)n * 100 + c0] = r0 + g.bias[c0];
    if (has1) g.outp[(size_t)n * 100 + c1] = r1 + g.bias[c1];
}

extern "C" void kernel_launch(void* const* d_in, const int* in_sizes, int n_in,
                              void* d_out, int out_size, void* d_ws, size_t ws_size,
                              hipStream_t stream) {
    const float* x_A   = (const float*)d_in[0];
    const float* x_B   = (const float*)d_in[1];
    const int*   ei_AB = (const int*)d_in[2];
    const int*   ei_BA = (const int*)d_in[3];
    const float* w_AB  = (const float*)d_in[4];
    const float* w_BA  = (const float*)d_in[5];
    const float* l1AB_Ws = (const float*)d_in[6];
    const float* l1AB_Wd = (const float*)d_in[7];
    const float* l1AB_as = (const float*)d_in[8];
    const float* l1AB_ad = (const float*)d_in[9];
    const float* l1AB_We = (const float*)d_in[10];
    const float* l1AB_ae = (const float*)d_in[11];
    const float* l1AB_b  = (const float*)d_in[12];
    const float* l2AB_Ws = (const float*)d_in[13];
    const float* l2AB_Wd = (const float*)d_in[14];
    const float* l2AB_as = (const float*)d_in[15];
    const float* l2AB_ad = (const float*)d_in[16];
    const float* l2AB_b  = (const float*)d_in[17];
    const float* l1BA_Ws = (const float*)d_in[18];
    const float* l1BA_Wd = (const float*)d_in[19];
    const float* l1BA_as = (const float*)d_in[20];
    const float* l1BA_ad = (const float*)d_in[21];
    const float* l1BA_We = (const float*)d_in[22];
    const float* l1BA_ae = (const float*)d_in[23];
    const float* l1BA_b  = (const float*)d_in[24];
    const float* l2BA_Ws = (const float*)d_in[25];
    const float* l2BA_Wd = (const float*)d_in[26];
    const float* l2BA_as = (const float*)d_in[27];
    const float* l2BA_ad = (const float*)d_in[28];
    const float* l2BA_b  = (const float*)d_in[29];

    const int N = NNODES, E = NEDGES;

    // ---- workspace carve (4-byte elements, 64-element aligned) ----
    size_t o = 0;
    auto alloc = [&](size_t n) { size_t r = o; o += (n + 63) & ~(size_t)63; return r; };
    size_t cntA = alloc(N), cntB = alloc(N);
    size_t roA = alloc(N + 1), roB = alloc(N + 1);
    size_t curA = alloc(N), curB = alloc(N);
    size_t ssA = alloc(E), ssB = alloc(E);
    size_t swA = alloc(E), swB = alloc(E);
    size_t ce8 = alloc(8);
    size_t part = alloc(128);
    size_t pHAB = alloc((size_t)N * 52);  // packed bf16 [N][104] as uints
    size_t pHBA = alloc((size_t)N * 52);
    size_t ad1B = alloc((size_t)N * 4), ad1A = alloc((size_t)N * 4);
    size_t hA1 = alloc((size_t)N * 100), hB1 = alloc((size_t)N * 100);
    size_t H2AB = alloc((size_t)N * 100), H2BA = alloc((size_t)N * 100);
    size_t as2AB = alloc(N), as2BA = alloc(N);
    size_t ad2AB = alloc(N), ad2BA = alloc(N);
    (void)ws_size;

    float* wsf = (float*)d_ws;
    int*   wsi = (int*)d_ws;
    u32*   wsu = (u32*)d_ws;

    // zero edge-count histograms (cntA..cntB contiguous span)
    hipMemsetAsync(wsi + cntA, 0, sizeof(int) * (cntB + N - cntA), stream);

    ce_kernel<<<2, 128, 0, stream>>>(l1AB_We, l1AB_ae, l1BA_We, l1BA_ae, wsf + ce8);

    const int eb = (2 * E + 255) / 256;
    count_kernel<<<eb, 256, 0, stream>>>(ei_AB, ei_BA, E, wsi + cntA, wsi + cntB);
    scanA_kernel<<<dim3(SCAN_NBLK, 2), SCAN_T, 0, stream>>>(
        wsi + cntA, wsi + cntB, wsi + roA, wsi + roB, wsi + part, N);
    scanB_kernel<<<1, 128, 0, stream>>>(wsi + part, SCAN_NBLK);
    scanC_kernel<<<dim3(SCAN_NBLK, 2), SCAN_T, 0, stream>>>(
        wsi + cntA, wsi + cntB, wsi + roA, wsi + roB, wsi + curA, wsi + curB, wsi + part, N);
    fill_kernel<<<eb, 256, 0, stream>>>(ei_AB, ei_BA, w_AB, w_BA, E, wsi + curA, wsi + curB,
                                        wsi + ssA, wsi + ssB, wsf + swA, wsf + swB);

    const int gb = (N + 127) / 128;  // 391
    // layer-1 node transforms (src roles -> packed bf16 tables; dst roles -> a_dst only)
    {
        GemmArgs g0 = {x_A, l1AB_Ws, l1AB_as, (void*)(wsu + pHAB), nullptr};
        GemmArgs g1 = {x_B, l1AB_Wd, l1AB_ad, nullptr, wsf + ad1B};
        GemmArgs g2 = {x_B, l1BA_Ws, l1BA_as, (void*)(wsu + pHBA), nullptr};
        GemmArgs g3 = {x_A, l1BA_Wd, l1BA_ad, nullptr, wsf + ad1A};
        gemm_att_kernel<128, 4><<<dim3(gb, 4), 256, 0, stream>>>(g0, g1, g2, g3, N);
    }

    const int wb = (N + 3) / 4;  // wave per node, 4 waves/block
    {
        Gather4Args g0 = {wsi + roA, wsi + ssA, wsf + swA, (const u16*)(wsu + pHAB),
                          wsf + ad1B, wsf + ce8, l1AB_b, wsf + hB1};
        Gather4Args g1 = {wsi + roB, wsi + ssB, wsf + swB, (const u16*)(wsu + pHBA),
                          wsf + ad1A, wsf + ce8 + 4, l1BA_b, wsf + hA1};
        gather4_kernel<<<dim3(wb, 2), 256, 0, stream>>>(g0, g1, N);
    }

    // layer-2 node transforms (src roles -> fp32 H + as; dst roles -> ad only)
    {
        GemmArgs g0 = {wsf + hA1, l2AB_Ws, l2AB_as, (void*)(wsf + H2AB), wsf + as2AB};
        GemmArgs g1 = {wsf + hB1, l2AB_Wd, l2AB_ad, nullptr, wsf + ad2AB};
        GemmArgs g2 = {wsf + hB1, l2BA_Ws, l2BA_as, (void*)(wsf + H2BA), wsf + as2BA};
        GemmArgs g3 = {wsf + hA1, l2BA_Wd, l2BA_ad, nullptr, wsf + ad2BA};
        gemm_att_kernel<100, 1><<<dim3(gb, 4), 256, 0, stream>>>(g0, g1, g2, g3, N);
    }

    float* out = (float*)d_out;
    // oA = BA direction (dst in A) -> d_out[0..5M); oB = AB direction -> d_out[5M..10M)
    {
        Gather1Args g0 = {wsi + roA, wsi + ssA, wsf + H2AB, wsf + as2AB, wsf + ad2AB,
                          l2AB_b, out + (size_t)N * 100};
        Gather1Args g1 = {wsi + roB, wsi + ssB, wsf + H2BA, wsf + as2BA, wsf + ad2BA,
                          l2BA_b, out};
        gather1_kernel<<<dim3(wb, 2), 256, 0, stream>>>(g0, g1, N);
    }
}